// Round 3
// baseline (61.351 us; speedup 1.0000x reference)
//
#include <hip/hip_runtime.h>

#define NS   88     // species
#define CCH  128    // channels
#define GY   16     // atom stripes per species in main kernel
#define BCAP 16384  // per-species bucket capacity

typedef float f32x4 __attribute__((ext_vector_type(4)));

// ---------------- coefficient table build (per s,c thread) ----------------
// T layout: [s][c][34][4]  -- row of 136 floats per (s,c).
// monomial m: 0..19 cubic multisets (a<=b<=d), 20..29 pairs (a<=b), 30..33 linear.
// component i at T[...][m][IST+i]: IST=0 -> 0e (1 comp), IST=1 -> 1o (3 comps).

template <int K3, int IST, int I>
__device__ void build_table(const float* __restrict__ u3, const float* __restrict__ w3,
                            const float* __restrict__ u2, const float* __restrict__ w2,
                            const float* __restrict__ u1, const float* __restrict__ w1,
                            int s, int c, float* __restrict__ Tsc) {
    float wk3[K3];
#pragma unroll
    for (int k = 0; k < K3; ++k) wk3[k] = w3[(s * K3 + k) * CCH + c];
    float wk2[2];
#pragma unroll
    for (int k = 0; k < 2; ++k) wk2[k] = w2[(s * 2 + k) * CCH + c];
    float wk1 = w1[s * CCH + c];

    // cubic: symmetrized over distinct permutations = (sum all 6 orderings) / rep
    int m = 0;
#pragma unroll
    for (int a = 0; a < 4; ++a)
#pragma unroll
    for (int b = a; b < 4; ++b)
#pragma unroll
    for (int d = b; d < 4; ++d) {
        float acc[I];
#pragma unroll
        for (int i = 0; i < I; ++i) acc[i] = 0.f;
        const int P[6][3] = {{a,b,d},{a,d,b},{b,a,d},{b,d,a},{d,a,b},{d,b,a}};
#pragma unroll
        for (int p = 0; p < 6; ++p) {
            int base = ((P[p][0] * 4 + P[p][1]) * 4 + P[p][2]) * (K3 * I);
#pragma unroll
            for (int k = 0; k < K3; ++k)
#pragma unroll
            for (int i = 0; i < I; ++i)
                acc[i] += u3[base + k * I + i] * wk3[k];
        }
        float inv = (a == d) ? (1.f / 6.f) : ((a == b || b == d) ? 0.5f : 1.f);
#pragma unroll
        for (int i = 0; i < I; ++i) Tsc[m * 4 + IST + i] = acc[i] * inv;
        ++m;
    }
    // quadratic
    int m2 = 0;
#pragma unroll
    for (int a = 0; a < 4; ++a)
#pragma unroll
    for (int b = a; b < 4; ++b) {
        float acc[I];
#pragma unroll
        for (int i = 0; i < I; ++i) acc[i] = 0.f;
#pragma unroll
        for (int k = 0; k < 2; ++k)
#pragma unroll
        for (int i = 0; i < I; ++i) {
            acc[i] += u2[((a * 4 + b) * 2 + k) * I + i] * wk2[k];
            if (a != b) acc[i] += u2[((b * 4 + a) * 2 + k) * I + i] * wk2[k];
        }
#pragma unroll
        for (int i = 0; i < I; ++i) Tsc[(20 + m2) * 4 + IST + i] = acc[i];
        ++m2;
    }
    // linear
#pragma unroll
    for (int d = 0; d < 4; ++d)
#pragma unroll
    for (int i = 0; i < I; ++i)
        Tsc[(30 + d) * 4 + IST + i] = u1[d * I + i] * wk1;
}

// ---------------- fused setup kernel ----------------
// blocks [0, NS): per-species wave-chunked ordered compaction into bucket[s][*].
//   4 waves each own N/4; pass1 count (no barriers), 1 barrier, pass2 scatter
//   with wave-local ballot prefix (no barriers). Deterministic, atomic-free.
// blocks [NS, NS+44): coefficient table build (256 threads = 2 (s,c)-rows).

__global__ __launch_bounds__(256) void k_setup(
    const int* __restrict__ species, int N,
    const float* u1_0e, const float* w1_0e, const float* u1_1o, const float* w1_1o,
    const float* u2_0e, const float* w2_0e, const float* u2_1o, const float* w2_1o,
    const float* u3_0e, const float* w3_0e, const float* u3_1o, const float* w3_1o,
    float* __restrict__ T, int* __restrict__ counts, int* __restrict__ list) {
    if (blockIdx.x < NS) {
        int s = blockIdx.x;
        int tid = threadIdx.x, lane = tid & 63, w = tid >> 6;
        __shared__ int wcnt[4];
        int chunk = (N + 3) >> 2;
        int cbeg = w * chunk, cend = min(N, cbeg + chunk);
        // pass 1: per-wave match count (ballot -> same value in all lanes)
        int cnt = 0;
        for (int base = cbeg; base < cend; base += 64) {
            int n = base + lane;
            bool m = (n < cend) && (species[n] == s);
            cnt += __popcll(__ballot(m));
        }
        if (lane == 0) wcnt[w] = cnt;
        __syncthreads();
        int pos = 0;
#pragma unroll
        for (int i = 0; i < 4; ++i) if (i < w) pos += wcnt[i];
        // pass 2: wave-local ordered scatter
        int* bucket = list + s * BCAP;
        for (int base = cbeg; base < cend; base += 64) {
            int n = base + lane;
            bool m = (n < cend) && (species[n] == s);
            unsigned long long b = __ballot(m);
            int rank = __popcll(b & ((1ull << lane) - 1));
            if (m) bucket[pos + rank] = n;
            pos += __popcll(b);
        }
        if (tid == 0) counts[s] = wcnt[0] + wcnt[1] + wcnt[2] + wcnt[3];
    } else {
        int t = (blockIdx.x - NS) * 256 + threadIdx.x;   // 44*256 = 88*128 exactly
        int s = t >> 7, c = t & 127;
        float* Tsc = T + ((size_t)s * CCH + c) * 136;
        build_table<4, 0, 1>(u3_0e, w3_0e, u2_0e, w2_0e, u1_0e, w1_0e, s, c, Tsc);
        build_table<6, 1, 3>(u3_1o, w3_1o, u2_1o, w2_1o, u1_1o, w1_1o, s, c, Tsc);
    }
}

// ---------------- main kernel ----------------
// Block = 128 threads (one channel each), blockIdx.x = species, blockIdx.y = stripe.
// 34 x f32x4 coef rows in VGPRs, reused across the stripe's atoms; next atom's x
// prefetched during compute. x-loads / out-stores are non-temporal so the 6.1 MB
// coefficient table stays L2-resident across the GY replications.

__global__ __launch_bounds__(128, 2) void k_main(
    const float* __restrict__ x, const float* __restrict__ T,
    const int* __restrict__ list, const int* __restrict__ counts,
    float* __restrict__ out) {
    int s = blockIdx.x;
    int c = threadIdx.x;
    int cnt = counts[s];
    int t = (int)blockIdx.y;
    if (t >= cnt) return;
    const int* bucket = list + s * BCAP;

    const f32x4* Tsc = reinterpret_cast<const f32x4*>(T + ((size_t)s * CCH + c) * 136);
    f32x4 coef[34];
#pragma unroll
    for (int m = 0; m < 34; ++m) coef[m] = Tsc[m];

    int n = bucket[t];
    f32x4 xv = __builtin_nontemporal_load(
        reinterpret_cast<const f32x4*>(x + (size_t)n * 512 + (c << 2)));

    while (true) {
        int tn = t + GY;
        bool more = tn < cnt;
        int nn = 0;
        f32x4 xn = (f32x4)(0.f);
        if (more) {
            nn = bucket[tn];
            xn = __builtin_nontemporal_load(
                reinterpret_cast<const f32x4*>(x + (size_t)nn * 512 + (c << 2)));
        }

        float xa[4] = {xv.x, xv.y, xv.z, xv.w};
        float mono[34];
        int q = 0;
#pragma unroll
        for (int a = 0; a < 4; ++a)
#pragma unroll
        for (int b = a; b < 4; ++b) { mono[20 + q] = xa[a] * xa[b]; ++q; }
        int m3 = 0;
#pragma unroll
        for (int a = 0; a < 4; ++a)
#pragma unroll
        for (int b = a; b < 4; ++b)
#pragma unroll
        for (int d = b; d < 4; ++d) { mono[m3] = mono[20 + (a * (7 - a)) / 2 + b] * xa[d]; ++m3; }
#pragma unroll
        for (int d = 0; d < 4; ++d) mono[30 + d] = xa[d];

        float o0 = 0.f, o1 = 0.f, o2 = 0.f, o3 = 0.f;
#pragma unroll
        for (int m = 0; m < 34; ++m) {
            float mv = mono[m];
            o0 = fmaf(coef[m].x, mv, o0);
            o1 = fmaf(coef[m].y, mv, o1);
            o2 = fmaf(coef[m].z, mv, o2);
            o3 = fmaf(coef[m].w, mv, o3);
        }
        float* orow = out + (size_t)n * 512;
        __builtin_nontemporal_store(o0, orow + c);
        __builtin_nontemporal_store(o1, orow + CCH + 3 * c + 0);
        __builtin_nontemporal_store(o2, orow + CCH + 3 * c + 1);
        __builtin_nontemporal_store(o3, orow + CCH + 3 * c + 2);

        if (!more) break;
        t = tn; n = nn; xv = xn;
    }
}

// ---------------- launch ----------------

extern "C" void kernel_launch(void* const* d_in, const int* in_sizes, int n_in,
                              void* d_out, int out_size, void* d_ws, size_t ws_size,
                              hipStream_t stream) {
    const float* x     = (const float*)d_in[0];
    const float* u1_0e = (const float*)d_in[1];
    const float* w1_0e = (const float*)d_in[2];
    const float* u1_1o = (const float*)d_in[3];
    const float* w1_1o = (const float*)d_in[4];
    const float* u2_0e = (const float*)d_in[5];
    const float* w2_0e = (const float*)d_in[6];
    const float* u2_1o = (const float*)d_in[7];
    const float* w2_1o = (const float*)d_in[8];
    const float* u3_0e = (const float*)d_in[9];
    const float* w3_0e = (const float*)d_in[10];
    const float* u3_1o = (const float*)d_in[11];
    const float* w3_1o = (const float*)d_in[12];
    const int*   spec  = (const int*)d_in[13];
    int N = in_sizes[13];
    float* out = (float*)d_out;

    char* ws = (char*)d_ws;
    float* T    = (float*)ws;                                // NS*CCH*136 floats
    size_t tbytes = (size_t)NS * CCH * 136 * sizeof(float);
    int* list   = (int*)(ws + tbytes);                       // NS*BCAP ints
    int* counts = list + NS * BCAP;                          // NS ints

    int table_blocks = (NS * CCH) / 256;                     // 44
    k_setup<<<NS + table_blocks, 256, 0, stream>>>(
        spec, N,
        u1_0e, w1_0e, u1_1o, w1_1o,
        u2_0e, w2_0e, u2_1o, w2_1o,
        u3_0e, w3_0e, u3_1o, w3_1o,
        T, counts, list);
    k_main<<<dim3(NS, GY), 128, 0, stream>>>(x, T, list, counts, out);
}